// Round 15
// baseline (419.023 us; speedup 1.0000x reference)
//
#include <hip/hip_runtime.h>
#include <hip/hip_bf16.h>

#define H 64
#define F 128
#define G4 256   // 4*H
#define T 512
#define B 512

typedef __attribute__((ext_vector_type(4))) float f32x4;
typedef __attribute__((ext_vector_type(8))) short bf16x8;

__device__ __forceinline__ short f2bf(float f) {
    union { float f; unsigned u; } v; v.f = f;
    unsigned r = (v.u + 0x7fffu + ((v.u >> 16) & 1u)) >> 16;
    return (short)r;
}
__device__ __forceinline__ short f2bf_cvt(float f) {
    unsigned r;
    asm("v_cvt_pk_bf16_f32 %0, %1, %1" : "=v"(r) : "v"(f));
    return (short)r;
}
__device__ __forceinline__ unsigned cvtpk(float lo, float hi) {
    unsigned r;
    asm("v_cvt_pk_bf16_f32 %0, %1, %2" : "=v"(r) : "v"(lo), "v"(hi));
    return r;
}

// ---------------------------------------------------------------------------
// Fused bidirectional LSTM: block = (dir, 4-row tile), 256 blocks, 4 waves.
// Per step (R9's verified rec structure + x.W fused into the stall cycles):
//   chain:    ds_read h-frags -> 8 h.U MFMAs -> z write (lq==0) -> barrier ->
//             z read (all 256 thr, 1 unit each) -> 8 trans gates -> h write ->
//             barrier
//   off-chain: ds_read staged x -> cvt -> 16 x.W MFMAs into the same acc
//             (bias-initialized); raw x staged 4 steps deep via
//             global_load_lds width-4 (wave w stages row w), vmcnt(6) BEFORE
//             the end-of-step barrier so other waves' rows are visible.
// xp never materializes: no xw_gemm kernel, no 536 MB HBM round-trip, and
// z_x stays fp32 (one less bf16 rounding than the split pipeline).
// ---------------------------------------------------------------------------
#define STAGEX(LT) do {                                                        \
    int _lt = (LT); if (_lt > T - 1) _lt = T - 1;                              \
    int _tt = dir ? (T - 1 - _lt) : _lt;                                       \
    const char* _g = (const char*)x                                            \
        + ((size_t)(r0 + w) * T + _tt) * 512 + 4 * l;                          \
    char* _lb = xbuf + (_lt & 3) * 2048 + w * 512;                             \
    __builtin_amdgcn_global_load_lds(                                          \
        (const __attribute__((address_space(1))) void*)_g,                     \
        (__attribute__((address_space(3))) void*)_lb, 4, 0, 0);                \
    __builtin_amdgcn_global_load_lds(                                          \
        (const __attribute__((address_space(1))) void*)(_g + 256),             \
        (__attribute__((address_space(3))) void*)(_lb + 256), 4, 0, 0);        \
} while (0)

#define RSTEP(TCUR, PRD, PWR) do {                                             \
    bf16x8 hf0 = *(const bf16x8*)(hlds + (PRD) * 2048 + rd_off);               \
    bf16x8 hf1 = *(const bf16x8*)(hlds + (PRD) * 2048 + 1024 + rd_off);        \
    /* off-chain: x A-fragments from staged raw x (row = l&3, k = 4lq+e) */    \
    bf16x8 af[4];                                                              \
    {                                                                          \
        const char* _xb = xbuf + ((TCUR) & 3) * 2048 + (l & 3) * 512 + lq * 16;\
        _Pragma("unroll")                                                      \
        for (int kt = 0; kt < 4; ++kt) {                                       \
            f32x4 a = *(const f32x4*)(_xb + kt * 128);                         \
            f32x4 b = *(const f32x4*)(_xb + kt * 128 + 64);                    \
            uint4 u;                                                           \
            u.x = cvtpk(a[0], a[1]); u.y = cvtpk(a[2], a[3]);                  \
            u.z = cvtpk(b[0], b[1]); u.w = cvtpk(b[2], b[3]);                  \
            af[kt] = *(bf16x8*)&u;                                             \
        }                                                                      \
    }                                                                          \
    f32x4 acc[4];                                                              \
    _Pragma("unroll")                                                          \
    for (int s = 0; s < 4; ++s)                                                \
        acc[s] = (f32x4){bsc[s], bsc[s], bsc[s], bsc[s]};                      \
    _Pragma("unroll")                                                          \
    for (int kt = 0; kt < 4; ++kt)                                             \
        _Pragma("unroll")                                                      \
        for (int s = 0; s < 4; ++s)                                            \
            acc[s] = __builtin_amdgcn_mfma_f32_16x16x32_bf16(                  \
                af[kt], wfr[kt][s], acc[s], 0, 0, 0);                          \
    _Pragma("unroll")                                                          \
    for (int s = 0; s < 4; ++s)                                                \
        acc[s] = __builtin_amdgcn_mfma_f32_16x16x32_bf16(                      \
            hf0, ufr[0][s], acc[s], 0, 0, 0);                                  \
    _Pragma("unroll")                                                          \
    for (int s = 0; s < 4; ++s)                                                \
        acc[s] = __builtin_amdgcn_mfma_f32_16x16x32_bf16(                      \
            hf1, ufr[1][s], acc[s], 0, 0, 0);                                  \
    if (lq == 0) {                                                             \
        _Pragma("unroll")                                                      \
        for (int e = 0; e < 4; ++e) {                                          \
            f32x4 zw = {acc[0][e], acc[1][e], acc[2][e], acc[3][e]};           \
            *(f32x4*)(zbc + e * 1024 + w * 256 + lr * 16) = zw;                \
        }                                                                      \
    }                                                                          \
    asm volatile("s_waitcnt lgkmcnt(0)" ::: "memory");                         \
    __builtin_amdgcn_s_barrier();                                              \
    __builtin_amdgcn_sched_barrier(0);                                         \
    {                                                                          \
        f32x4 zv = *(const f32x4*)(zbc + tid * 16);                            \
        float ei = __expf(-zv[0]);                                             \
        float ef = __expf(-zv[1]);                                             \
        float eg = __expf(2.f * fminf(zv[2], 15.f));                           \
        float sf = __builtin_amdgcn_rcpf(1.f + ef);                            \
        float dig = __builtin_amdgcn_rcpf((1.f + ei) * (1.f + eg));            \
        cc = fmaf(sf, cc, (eg - 1.f) * dig);                                   \
        float eo = __expf(-zv[3]);                                             \
        float ec = __expf(2.f * fminf(cc, 15.f));                              \
        float doc = __builtin_amdgcn_rcpf((1.f + eo) * (1.f + ec));            \
        hh = (ec - 1.f) * doc;                                                 \
        *(short*)(hlds + (PWR) * 2048 + wr) = f2bf_cvt(hh);                    \
    }                                                                          \
    STAGEX((TCUR) + 4);                                                        \
    asm volatile("s_waitcnt lgkmcnt(0)" ::: "memory");                         \
    asm volatile("s_waitcnt vmcnt(6)" ::: "memory");                           \
    __builtin_amdgcn_sched_barrier(0);                                         \
    __builtin_amdgcn_s_barrier();                                              \
    __builtin_amdgcn_sched_barrier(0);                                         \
} while (0)

__global__ __launch_bounds__(256, 1)
void lstm_fused(const float* __restrict__ x,
                const float* __restrict__ Wf, const float* __restrict__ Uf,
                const float* __restrict__ bfv,
                const float* __restrict__ Wb, const float* __restrict__ Ub,
                const float* __restrict__ bbv,
                float* __restrict__ hcat /* [B][2H] */) {
    const int tid = threadIdx.x;
    const int l = tid & 63, w = tid >> 6;
    const int lq = l >> 4, lr = l & 15;
    const int dir = blockIdx.x >> 7;
    const int rowg = blockIdx.x & 127;   // 4-row tile index
    const int r0 = rowg * 4;

    const float* __restrict__ Wm = dir ? Wb : Wf;
    const float* __restrict__ Um = dir ? Ub : Uf;
    const float* __restrict__ bv = dir ? bbv : bfv;

    // wave w, N-family s: col = (w+4s)*16 + lr = gate s of unit 16w+lr
    bf16x8 wfr[4][4];
#pragma unroll
    for (int kt = 0; kt < 4; ++kt)
#pragma unroll
        for (int s = 0; s < 4; ++s) {
            int col = (w + 4 * s) * 16 + lr;
            int k0 = kt * 32 + 4 * lq;
            bf16x8 v;
#pragma unroll
            for (int e = 0; e < 4; ++e) {
                v[e]     = f2bf(Wm[(k0 + e) * G4 + col]);
                v[e + 4] = f2bf(Wm[(k0 + 16 + e) * G4 + col]);
            }
            wfr[kt][s] = v;
        }
    bf16x8 ufr[2][4];
#pragma unroll
    for (int kt = 0; kt < 2; ++kt)
#pragma unroll
        for (int s = 0; s < 4; ++s) {
            int col = (w + 4 * s) * 16 + lr;
            int k0 = kt * 32 + 4 * lq;
            bf16x8 v;
#pragma unroll
            for (int e = 0; e < 4; ++e) {
                v[e]     = f2bf(Um[(k0 + e) * G4 + col]);
                v[e + 4] = f2bf(Um[(k0 + 16 + e) * G4 + col]);
            }
            ufr[kt][s] = v;
        }
    float bsc[4];
#pragma unroll
    for (int s = 0; s < 4; ++s) bsc[s] = bv[(w + 4 * s) * 16 + lr];

    __shared__ __align__(16) char xbuf[4 * 2048];  // 4-deep raw x staging
    __shared__ __align__(16) char hlds[4096];      // h A-frag double buffer
    __shared__ __align__(16) char zbc[4096];       // z exchange [row][wp][lr]

    ((f32x4*)hlds)[tid] = (f32x4){0.f, 0.f, 0.f, 0.f};

    // prologue: stage x for steps 0..3 (8 loads/wave in flight)
    STAGEX(0);
    STAGEX(1);
    STAGEX(2);
    STAGEX(3);
    __syncthreads();   // drains vmcnt(0) + lgkm: everything staged & zeroed

    const int rd_off = (l * 16) ^ (((l >> 4) & 3) << 4);

    // gate thread (wave w, lane l) owns (row = w, unit j = l)
    int wr;
    {
        int fl = w + 16 * ((l >> 2) & 3);
        wr = (l >> 5) * 1024 + ((fl * 16) ^ (((fl >> 4) & 3) << 4))
             + ((l & 3) + 4 * ((l >> 4) & 1)) * 2;
    }

    float cc = 0.f, hh = 0.f;

    for (int t = 0; t < T; t += 2) {
        RSTEP(t,     0, 1);
        RSTEP(t + 1, 1, 0);
    }

    // final hidden state: thread owns (row = w, unit = l)
    hcat[(size_t)(r0 + w) * (2 * H) + dir * H + l] = hh;
}

// out[b][e] = relu(sum_k hcat[b][k] * Wd[k][e] + bd[e])   (fp32)
__global__ void dense_kernel(const float* __restrict__ hcat,
                             const float* __restrict__ Wd,
                             const float* __restrict__ bd,
                             float* __restrict__ out) {
    const int b = blockIdx.x;
    const int e = threadIdx.x;   // 128 threads
    float acc = bd[e];
#pragma unroll
    for (int k = 0; k < 2 * H; ++k)
        acc = fmaf(hcat[b * (2 * H) + k], Wd[k * 128 + e], acc);
    out[b * 128 + e] = fmaxf(acc, 0.f);
}

extern "C" void kernel_launch(void* const* d_in, const int* in_sizes, int n_in,
                              void* d_out, int out_size, void* d_ws, size_t ws_size,
                              hipStream_t stream) {
    const float* x       = (const float*)d_in[0];
    const float* W_fwd   = (const float*)d_in[1];
    const float* U_fwd   = (const float*)d_in[2];
    const float* b_fwd   = (const float*)d_in[3];
    const float* W_bwd   = (const float*)d_in[4];
    const float* U_bwd   = (const float*)d_in[5];
    const float* b_bwd   = (const float*)d_in[6];
    const float* W_dense = (const float*)d_in[7];
    const float* b_dense = (const float*)d_in[8];
    float* out = (float*)d_out;

    float* hcat = (float*)d_ws;   // [B][2H] fp32 = 256 KB

    lstm_fused<<<dim3(256), dim3(256), 0, stream>>>(
        x, W_fwd, U_fwd, b_fwd, W_bwd, U_bwd, b_bwd, hcat);

    dense_kernel<<<dim3(B), dim3(128), 0, stream>>>(hcat, W_dense, b_dense, out);
}